// Round 9
// baseline (490.750 us; speedup 1.0000x reference)
//
#include <hip/hip_runtime.h>
#include <hip/hip_bf16.h>

typedef __attribute__((ext_vector_type(8))) short bf16x8_t;   // MFMA A/B frag (8 bf16)
typedef __attribute__((ext_vector_type(4))) float f32x4_t;    // MFMA C/D frag
typedef __attribute__((ext_vector_type(4))) float fv4;
typedef __attribute__((ext_vector_type(4))) unsigned short us4_t;
typedef __attribute__((ext_vector_type(8))) unsigned short us8_t;

// Problem constants
static constexpr int BB = 16, NN = 4096, DD = 768, HH = 16, EE = 48;

__device__ __forceinline__ unsigned short f2bf(float f) {
  unsigned int u = __float_as_uint(f);
  u += 0x7fffu + ((u >> 16) & 1u);   // RNE; inputs are finite
  return (unsigned short)(u >> 16);
}
__device__ __forceinline__ float bf2f(unsigned short s) {
  unsigned int u = ((unsigned int)s) << 16;
  return __uint_as_float(u);
}

__device__ __forceinline__ void load_lds16(const void* g, void* l) {
  __builtin_amdgcn_global_load_lds((const __attribute__((address_space(1))) void*)g,
                                   (__attribute__((address_space(3))) void*)l, 16, 0, 0);
}

// ---------------------------------------------------------------------------
// 64x64 f32->bf16 transposing tile cast via LDS. dst[c][r] = src[r][c].
// Optional pass-through row-major bf16 write (thru).
// ---------------------------------------------------------------------------
template<int WRITE_THRU>
__device__ __forceinline__ void tcast64(const float* __restrict__ src, int sld,
                                        unsigned short* __restrict__ dst, int dld,
                                        unsigned short* __restrict__ thru, int tld, int t)
{
  __shared__ float L[64][65];
#pragma unroll
  for (int q = 0; q < 4; ++q) {
    const int fi = t + q * 256;          // 0..1023
    const int r = fi >> 4, c4 = fi & 15; // row, col-group of 4
    fv4 v = *(const fv4*)(src + (long)r * sld + c4 * 4);
    L[r][c4 * 4 + 0] = v.x; L[r][c4 * 4 + 1] = v.y;
    L[r][c4 * 4 + 2] = v.z; L[r][c4 * 4 + 3] = v.w;
    if (WRITE_THRU) {
      us4_t o; o.x = f2bf(v.x); o.y = f2bf(v.y); o.z = f2bf(v.z); o.w = f2bf(v.w);
      *(us4_t*)(thru + (long)r * tld + c4 * 4) = o;
    }
  }
  __syncthreads();
#pragma unroll
  for (int q = 0; q < 2; ++q) {
    const int wi = t + q * 256;          // 0..511
    const int rr = wi >> 3, ng = wi & 7; // dst row, 8-col group
    us8_t o;
#pragma unroll
    for (int j = 0; j < 8; ++j) o[j] = f2bf(L[ng * 8 + j][rr]);
    *(us8_t*)(dst + (long)rr * dld + ng * 8) = o;
  }
  __syncthreads();
}

// K1a: x -> xb (row-major bf16) AND xbT (transposed bf16 [b][d][n])
__global__ __launch_bounds__(256) void transpose_cast_x(
    const float* __restrict__ x, unsigned short* __restrict__ xb,
    unsigned short* __restrict__ xbT)
{
  const int nx = blockIdx.x, dx = blockIdx.y, b = blockIdx.z;
  const int n0 = nx * 64, d0 = dx * 64;
  const float* src = x + ((long)b * NN + n0) * DD + d0;
  unsigned short* thru = xb + ((long)b * NN + n0) * DD + d0;
  unsigned short* dst = xbT + ((long)b * DD + d0) * NN + n0;
  tcast64<1>(src, DD, dst, NN, thru, DD, threadIdx.x);
}

// K1b: W2=[wq;wk] bf16 [1536][768]; wvT bf16 [768(k)][768(i)] = wv^T; zeros
__global__ __launch_bounds__(256) void small_cast(
    const float* __restrict__ wq, const float* __restrict__ wk, const float* __restrict__ wv,
    unsigned short* __restrict__ W2, unsigned short* __restrict__ wvT,
    float* __restrict__ zeros)
{
  const int blk = blockIdx.x, t = threadIdx.x;
  if (blk < 576) {
    // 1536x768 = 1179648 elems = 576 blocks * 512 fv4-ish groups
#pragma unroll
    for (int q = 0; q < 2; ++q) {
      long g = (long)blk * 512 + t * 2 + q;   // fv4 index
      long e0 = g * 4;
      int row = (int)(e0 / DD), col = (int)(e0 % DD);
      const float* src = (row < DD) ? (wq + (long)row * DD + col)
                                    : (wk + (long)(row - DD) * DD + col);
      fv4 v = *(const fv4*)src;
      us4_t o; o.x = f2bf(v.x); o.y = f2bf(v.y); o.z = f2bf(v.z); o.w = f2bf(v.w);
      *(us4_t*)(W2 + e0) = o;
    }
  } else if (blk < 720) {
    const int tile = blk - 576;
    const int ti = tile / 12, tj = tile % 12;  // k-block, i-block
    const int k0 = ti * 64, i0 = tj * 64;
    // wvT[k][i] = wv[i][k]
    tcast64<0>(wv + (long)i0 * DD + k0, DD, wvT + (long)k0 * DD + i0, DD, nullptr, 0, t);
  } else {
#pragma unroll
    for (int q = 0; q < 4; ++q) zeros[t * 4 + q] = 0.f;
  }
}

// K1c: xsum[b][d] = sum_n x[b][n][d], read from xbT rows (contiguous).
__global__ __launch_bounds__(256) void colsum(
    const unsigned short* __restrict__ xbT, float* __restrict__ xsum)
{
  const int bx = blockIdx.x, b = blockIdx.y;
  const int wave = threadIdx.x >> 6, lane = threadIdx.x & 63;
  const int d = bx * 4 + wave;
  const unsigned short* row = xbT + ((long)b * DD + d) * NN;
  float s = 0.f;
#pragma unroll
  for (int it = 0; it < 8; ++it) {
    us8_t v = *(const us8_t*)(row + (it * 64 + lane) * 8);
#pragma unroll
    for (int j = 0; j < 8; ++j) s += bf2f(v[j]);
  }
#pragma unroll
  for (int off = 32; off > 0; off >>= 1) s += __shfl_down(s, off);
  if (lane == 0) xsum[(long)b * DD + d] = s;
}

// ---------------------------------------------------------------------------
// bf16 GEMM, C[m][n] = sum_k A[m][k] * Bt[n][k] + bias[n]  (per-z bias optional)
// 128x128 tile, BK=64, 4 waves (2x2 of 64x64), XOR-swizzled LDS (conflicts=0,
// round-7 verified), double-buffered.
// Round-9 fix (T4): round-8's __syncthreads drained vmcnt(0) INCLUDING the
// just-issued prefetch -> pipeline dead (134->140us regression). Now: raw
// s_barrier (no auto-drain) + counted inline-asm vmcnt.
// Schedule ledger (8 global_load_lds per STAGE per thread):
//   iter i: STAGE(buf[(i+1)%2])          // <=16 outstanding
//           s_waitcnt vmcnt(8)           // oldest 8 = tile i's loads (m135);
//                                        // prefetch stays in flight; last: 0
//           sched_barrier; s_barrier     // all waves: tile i in LDS
//           ds_read+MFMA on buf[i%2]     // lgkmcnt guards reads->MFMA
//           sched_barrier; s_barrier (E) // all waves done READING buf[i%2]
// WAR hazard: iter i+1 STAGE writes buf[i%2]; closed by (E).
// 1-D grid + XCD-chunked bijective swizzle (T1; all call sites nwg%8==0).
// SYM=1 (A==Bt, square): upper-triangle tiles only; mirror tile written
// transposed via packed us4. OUT_BF16=1 -> bf16 store, else f32 store.
// ---------------------------------------------------------------------------
template<int OUT_BF16, int SYM>
__global__ __launch_bounds__(256) void gemm_bt(
    const unsigned short* __restrict__ A, int lda, long aStride,
    const unsigned short* __restrict__ Bt, int ldb, long bStride,
    void* __restrict__ Cv, int ldc, long cStride,
    const float* __restrict__ bias, long biasStride, int K,
    int perB, int nt)
{
  __shared__ unsigned short As[2][128 * 64];
  __shared__ unsigned short Bs[2][128 * 64];
  const int nwg = gridDim.x;
  const int bid = blockIdx.x;
  const int wid = (bid & 7) * (nwg >> 3) + (bid >> 3);   // XCD-chunked
  const int zb = wid / perB;
  const int t0 = wid % perB;
  int i0, j0;
  if (SYM) {
    int tt = t0; i0 = 0;
    while (tt >= nt - i0) { tt -= nt - i0; ++i0; }
    j0 = i0 + tt;
  } else {
    i0 = t0 / nt; j0 = t0 % nt;   // n fastest: consecutive blocks share A-panel
  }
  const unsigned short* Ab = A + (long)zb * aStride;
  const unsigned short* Bb = Bt + (long)zb * bStride;
  const float* bz = bias + (long)zb * biasStride;
  const long m0 = (long)i0 * 128;
  const int n0 = j0 * 128;
  const int t = threadIdx.x;
  const int wave = t >> 6, lane = t & 63;
  const int wr = wave >> 1, wc = wave & 1;

  f32x4_t acc[4][4] = {};

  // staging: thread t covers LDS bytes p*4096 + t*16 (p=0..3, linear dest).
  // row = p*32 + (t>>3); block c = t&7; source block = c ^ (row&7).
  const int srow = t >> 3;                                // 0..31
  const long scol = (long)(((t & 7) ^ (srow & 7)) << 3);  // elems

  auto STAGE = [&](int bsel, int kt) {
#pragma unroll
    for (int p = 0; p < 4; ++p) {
      load_lds16(Ab + (m0 + p * 32 + srow) * (long)lda + kt + scol,
                 &As[bsel][wave * 512 + p * 2048]);
      load_lds16(Bb + (long)(n0 + p * 32 + srow) * ldb + kt + scol,
                 &Bs[bsel][wave * 512 + p * 2048]);
    }
  };

  STAGE(0, 0);

  int cur = 0;
  for (int kt = 0; kt < K; kt += 64) {
    if (kt + 64 < K) {
      STAGE(cur ^ 1, kt + 64);   // prefetch next tile; stays in flight
      asm volatile("s_waitcnt vmcnt(8)" ::: "memory");   // tile-cur loads done
    } else {
      asm volatile("s_waitcnt vmcnt(0)" ::: "memory");
    }
    __builtin_amdgcn_sched_barrier(0);
    __builtin_amdgcn_s_barrier();            // raw: no vmcnt auto-drain
#pragma unroll
    for (int kk = 0; kk < 2; ++kk) {
      // frag read (swizzled): row = W*64+f*16+(lane&15); logical blk = kk*4+(lane>>4)
      const int cswz = (((kk << 2) + (lane >> 4)) ^ (lane & 7)) << 4;   // bytes
      bf16x8_t af[4], bfr[4];
#pragma unroll
      for (int f = 0; f < 4; ++f) {
        af[f]  = *(const bf16x8_t*)((const char*)&As[cur][0] + (wr * 64 + f * 16 + (lane & 15)) * 128 + cswz);
        bfr[f] = *(const bf16x8_t*)((const char*)&Bs[cur][0] + (wc * 64 + f * 16 + (lane & 15)) * 128 + cswz);
      }
#pragma unroll
      for (int i = 0; i < 4; ++i)
#pragma unroll
        for (int j = 0; j < 4; ++j)
          acc[i][j] = __builtin_amdgcn_mfma_f32_16x16x32_bf16(af[i], bfr[j], acc[i][j], 0, 0, 0);
    }
    __builtin_amdgcn_sched_barrier(0);
    __builtin_amdgcn_s_barrier();            // (E) buf[cur] reads complete
    cur ^= 1;
  }

  // epilogue: D col = lane&15, row = (lane>>4)*4 + r  (m89-verified layout)
  const int col_l = lane & 15;
  const int rbase = (lane >> 4) << 2;
#pragma unroll
  for (int i = 0; i < 4; ++i) {
    const long growb = m0 + wr * 64 + i * 16 + rbase;
#pragma unroll
    for (int j = 0; j < 4; ++j) {
      const int col = n0 + wc * 64 + j * 16 + col_l;
      if (OUT_BF16) {
        const float bcol = bz[col];
        us4_t o;
#pragma unroll
        for (int r = 0; r < 4; ++r) o[r] = f2bf(acc[i][j][r] + bcol);
        unsigned short* cb = (unsigned short*)Cv + (long)zb * cStride;
#pragma unroll
        for (int r = 0; r < 4; ++r) cb[(growb + r) * ldc + col] = o[r];
        if (SYM && i0 != j0)   // mirror tile, transposed, packed 8B store
          *(us4_t*)(cb + (long)col * ldc + growb) = o;
      } else {
#pragma unroll
        for (int r = 0; r < 4; ++r) {
          float* crow = (float*)Cv + (long)zb * cStride + (growb + r) * ldc;
          crow[col] = acc[i][j][r] + bz[col];
        }
      }
    }
  }
}

// ---------------------------------------------------------------------------
// K3a: per (b,h,kc): partial E_h = Tq_h * wk_h^T over k' in [kc*384,+384),
// plus diag(Tq_h*wq_h^T) -> nq2, diag(Tk_h*wk_h^T) -> nk2 (MFMA diag trick).
// Tq_h = T[b] rows [h*48,+48), Tk_h = rows [768+h*48,+48); same for W2.
// Staged via global_load_lds with the round-4-proven 16B-block XOR swizzle
// (pre-swizzled global source + swizzled frag reads; rows 256B).
// Writes fp32 partials Gp[((b*H+h)*2+kc)][2464]:
//   [0..2352) = E (48 rows x stride 49), [2352..2400) nq2, [2400..2448) nk2.
// ---------------------------------------------------------------------------
#define GP_STRIDE 2464

__global__ __launch_bounds__(256) void energy_partial2(
    const unsigned short* __restrict__ T, const unsigned short* __restrict__ W2,
    float* __restrict__ Gp)
{
  __shared__ unsigned short Ts[2][48 * 128];   // Tq, Tk tiles (12KB each)
  __shared__ unsigned short Ws[2][48 * 128];   // wq, wk tiles
  __shared__ float G_sh[2448];

  const int kc = blockIdx.x, h = blockIdx.y, b = blockIdx.z;
  const int t = threadIdx.x;
  const int wave = t >> 6, lane = t & 63;

  for (int i = t; i < 2448; i += 256) G_sh[i] = 0.f;

  f32x4_t accG[3][3] = {};
  f32x4_t accQ[3] = {};
  f32x4_t accK[3] = {};

  // staging source offsets: linear LDS byte L = p*4096 + wave*1024 + lane*16
  // -> e = L>>8, 16B-block blk = (L>>4)&15; inverse-swizzled source k-block
  long qoff[3];
#pragma unroll
  for (int p = 0; p < 3; ++p) {
    const int L = p * 4096 + wave * 1024 + lane * 16;
    const int e = L >> 8;
    const int blk = (L >> 4) & 15;
    const int sblk = blk ^ (e & 7);
    qoff[p] = (long)e * DD + sblk * 8;
  }
  const unsigned short* Tq = T + ((long)b * 1536 + h * 48) * DD;
  const unsigned short* Tk = Tq + (long)DD * DD;
  const unsigned short* Wq = W2 + (long)h * 48 * DD;
  const unsigned short* Wk = Wq + (long)DD * DD;

  // frag read offsets (bytes, swizzled): e = f*16+(lane&15), k-blk = wave*4+(lane>>4)
  int foff[3];
#pragma unroll
  for (int f = 0; f < 3; ++f) {
    const int e = f * 16 + (lane & 15);
    foff[f] = e * 256 + (((wave * 4 + (lane >> 4)) ^ (e & 7)) << 4);
  }
  __syncthreads();

  for (int ci = 0; ci < 3; ++ci) {
    const int col0 = kc * 384 + ci * 128;
#pragma unroll
    for (int p = 0; p < 3; ++p) {
      load_lds16(Tq + qoff[p] + col0, &Ts[0][p * 2048] + wave * 512);
      load_lds16(Tk + qoff[p] + col0, &Ts[1][p * 2048] + wave * 512);
      load_lds16(Wq + qoff[p] + col0, &Ws[0][p * 2048] + wave * 512);
      load_lds16(Wk + qoff[p] + col0, &Ws[1][p * 2048] + wave * 512);
    }
    __syncthreads();
    bf16x8_t tq[3], tk[3], wqf[3], wkf[3];
#pragma unroll
    for (int f = 0; f < 3; ++f) {
      tq[f]  = *(const bf16x8_t*)((const char*)&Ts[0][0] + foff[f]);
      tk[f]  = *(const bf16x8_t*)((const char*)&Ts[1][0] + foff[f]);
      wqf[f] = *(const bf16x8_t*)((const char*)&Ws[0][0] + foff[f]);
      wkf[f] = *(const bf16x8_t*)((const char*)&Ws[1][0] + foff[f]);
    }
#pragma unroll
    for (int i = 0; i < 3; ++i) {
      accQ[i] = __builtin_amdgcn_mfma_f32_16x16x32_bf16(tq[i], wqf[i], accQ[i], 0, 0, 0);
      accK[i] = __builtin_amdgcn_mfma_f32_16x16x32_bf16(tk[i], wkf[i], accK[i], 0, 0, 0);
#pragma unroll
      for (int j = 0; j < 3; ++j)
        accG[i][j] = __builtin_amdgcn_mfma_f32_16x16x32_bf16(tq[i], wkf[j], accG[i][j], 0, 0, 0);
    }
    __syncthreads();
  }

  // cross-wave reduce into LDS
#pragma unroll
  for (int i = 0; i < 3; ++i)
#pragma unroll
    for (int j = 0; j < 3; ++j) {
      int e = i * 16 + ((lane >> 4) << 2);
      int qi = j * 16 + (lane & 15);
#pragma unroll
      for (int r = 0; r < 4; ++r) atomicAdd(&G_sh[(e + r) * 49 + qi], accG[i][j][r]);
    }
  // diagonal lanes contribute the norms
  if ((lane >> 4) == ((lane & 15) >> 2)) {
    int r = (lane & 15) & 3;
#pragma unroll
    for (int f = 0; f < 3; ++f) {
      atomicAdd(&G_sh[2352 + f * 16 + (lane & 15)], accQ[f][r]);
      atomicAdd(&G_sh[2400 + f * 16 + (lane & 15)], accK[f][r]);
    }
  }
  __syncthreads();

  float* out = Gp + (long)(((b * HH + h) << 1) + kc) * GP_STRIDE;
  for (int i = t; i < 2448; i += 256) out[i] = G_sh[i];
}

// ---------------------------------------------------------------------------
// K3b: per (b,h): reduce 2 partials, apply bias corrections (exact-zero-cost
// when bq=bk=0: runtime check skips them), norms, softmax, /tau.
// Writes A bf16 padded [48][64] (cols 48..63 zero) for build_btf.
// ---------------------------------------------------------------------------
__global__ __launch_bounds__(256) void energy_finish2(
    const float* __restrict__ Gp, const float* __restrict__ xsum,
    const float* __restrict__ wq, const float* __restrict__ wk,
    const float* __restrict__ bq, const float* __restrict__ bk,
    const float* __restrict__ tau_p, unsigned short* __restrict__ A_out)
{
  __shared__ float G_sh[2448];
  __shared__ float vq[48], vk[48], bqs[48], bks[48];
  __shared__ int has_bias;
  const int h = blockIdx.x, b = blockIdx.y;
  const int t = threadIdx.x;

  const float* base = Gp + (long)((b * HH + h) << 1) * GP_STRIDE;
  for (int i = t; i < 2448; i += 256)
    G_sh[i] = base[i] + base[GP_STRIDE + i];
  if (t < 48) { bqs[t] = bq[h * 48 + t]; bks[t] = bk[h * 48 + t]; }
  __syncthreads();
  if (t == 0) {
    float s = 0.f;
    for (int i = 0; i < 48; ++i) s += fabsf(bqs[i]) + fabsf(bks[i]);
    has_bias = (s != 0.f);
  }
  __syncthreads();
  if (has_bias) {
    // vq[e] = wq_h[e,:] . xsum[b],  vk[q] = wk_h[q,:] . xsum[b]
    if (t < 96) {
      const int e = t < 48 ? t : t - 48;
      const float* wrow = (t < 48 ? wq : wk) + (long)(h * 48 + e) * DD;
      const float* xs = xsum + (long)b * DD;
      float s = 0.f;
      for (int g = 0; g < DD / 4; ++g) {
        fv4 a = *(const fv4*)(wrow + g * 4);
        fv4 c = *(const fv4*)(xs + g * 4);
        s += a.x * c.x + a.y * c.y + a.z * c.z + a.w * c.w;
      }
      if (t < 48) vq[e] = s; else vk[e] = s;
    }
  } else if (t < 48) { vq[t] = 0.f; vk[t] = 0.f; }
  __syncthreads();

  if (t < 48) {
    const float tau = *tau_p;
    const float nq2c = G_sh[2352 + t] + 2.f * bqs[t] * vq[t] + (float)NN * bqs[t] * bqs[t];
    const float nq = fmaxf(sqrtf(nq2c), 1e-12f);
    float row[48];
    float mx = -1e30f;
#pragma unroll 1
    for (int qi = 0; qi < 48; ++qi) {
      float nk2c = G_sh[2400 + qi] + 2.f * bks[qi] * vk[qi] + (float)NN * bks[qi] * bks[qi];
      float nk = fmaxf(sqrtf(nk2c), 1e-12f);
      float e = G_sh[t * 49 + qi] + vq[t] * bks[qi] + bqs[t] * vk[qi]
              + (float)NN * bqs[t] * bks[qi];
      float g = e / (nq * nk);
      row[qi] = g; mx = fmaxf(mx, g);
    }
    float s = 0.f;
#pragma unroll 1
    for (int qi = 0; qi < 48; ++qi) { row[qi] = __expf(row[qi] - mx); s += row[qi]; }
    const float inv = 1.f / (s * tau);
    unsigned short* dst = A_out + (((long)b * HH + h) * 48) * 64 + (long)t * 64;
#pragma unroll 1
    for (int qi = 0; qi < 48; ++qi) dst[qi] = f2bf(row[qi] * inv);
#pragma unroll 1
    for (int qi = 48; qi < 64; ++qi) dst[qi] = 0;
  }
}

// ---------------------------------------------------------------------------
// K4: Btf[b][no][h*48+e] = sum_qi A_h[e][qi] * wo[no][h*48+qi]   (MFMA, K=48
// padded to 64). A-operand = wo rows (qi-contiguous), B-operand = A_h rows.
// ---------------------------------------------------------------------------
__global__ __launch_bounds__(256) void build_btf(
    const unsigned short* __restrict__ A_ws, const float* __restrict__ wo,
    unsigned short* __restrict__ btf)
{
  __shared__ unsigned short Wsh[128 * 72];
  __shared__ unsigned short Ash[48 * 72];
  const int nchunk = blockIdx.x, h = blockIdx.y, b = blockIdx.z;
  const int t = threadIdx.x;
  const int wave = t >> 6, lane = t & 63;
  const int no0 = nchunk * 128;

  for (int i = t; i < 128 * 64; i += 256) {
    int r = i >> 6, c = i & 63;
    Wsh[r * 72 + c] = (c < 48) ? f2bf(wo[(long)(no0 + r) * DD + h * 48 + c]) : (unsigned short)0;
  }
  const unsigned short* Asrc = A_ws + ((long)b * HH + h) * 48 * 64;
  for (int i = t; i < 48 * 64; i += 256) {
    int r = i >> 6, c = i & 63;
    Ash[r * 72 + c] = Asrc[r * 64 + c];   // already zero-padded in cols 48..63
  }
  __syncthreads();

  f32x4_t acc[2][3] = {};
#pragma unroll
  for (int ks = 0; ks < 2; ++ks) {
    const int k0 = ks * 32 + ((lane >> 4) << 3);
    bf16x8_t af[2], bfr[3];
#pragma unroll
    for (int mi = 0; mi < 2; ++mi)
      af[mi] = *(const bf16x8_t*)&Wsh[(wave * 32 + mi * 16 + (lane & 15)) * 72 + k0];
#pragma unroll
    for (int nj = 0; nj < 3; ++nj)
      bfr[nj] = *(const bf16x8_t*)&Ash[(nj * 16 + (lane & 15)) * 72 + k0];
#pragma unroll
    for (int mi = 0; mi < 2; ++mi)
#pragma unroll
      for (int nj = 0; nj < 3; ++nj)
        acc[mi][nj] = __builtin_amdgcn_mfma_f32_16x16x32_bf16(af[mi], bfr[nj], acc[mi][nj], 0, 0, 0);
  }

  const int col_l = lane & 15;
  const int rbase = (lane >> 4) << 2;
#pragma unroll
  for (int mi = 0; mi < 2; ++mi)
#pragma unroll
    for (int r = 0; r < 4; ++r) {
      int no = no0 + wave * 32 + mi * 16 + rbase + r;
      unsigned short* dst = btf + ((long)b * DD + no) * DD + h * 48;
#pragma unroll
      for (int nj = 0; nj < 3; ++nj)
        dst[nj * 16 + col_l] = f2bf(acc[mi][nj][r]);
    }
}

// ---------------------------------------------------------------------------
// K5: bias2[b][j] = bo[j] + sum_i bv[i]*Btf[b][j][i]
// ---------------------------------------------------------------------------
__global__ __launch_bounds__(256) void build_bias2(
    const unsigned short* __restrict__ btf, const float* __restrict__ bv,
    const float* __restrict__ bo, float* __restrict__ bias2)
{
  const int bx = blockIdx.x, b = blockIdx.y;
  const int wave = threadIdx.x >> 6, lane = threadIdx.x & 63;
  const int j = bx * 4 + wave;
  const unsigned short* row = btf + ((long)b * DD + j) * DD;
  float s = 0.f;
#pragma unroll
  for (int ii = 0; ii < 12; ++ii) {
    int i = ii * 64 + lane;
    s += bf2f(row[i]) * bv[i];
  }
#pragma unroll
  for (int off = 32; off > 0; off >>= 1) s += __shfl_down(s, off);
  if (lane == 0) bias2[(long)b * DD + j] = bo[j] + s;
}

// ---------------------------------------------------------------------------
extern "C" void kernel_launch(void* const* d_in, const int* in_sizes, int n_in,
                              void* d_out, int out_size, void* d_ws, size_t ws_size,
                              hipStream_t stream)
{
  (void)in_sizes; (void)n_in; (void)out_size;
  const float* x   = (const float*)d_in[0];
  const float* wq  = (const float*)d_in[1];
  const float* bq  = (const float*)d_in[2];
  const float* wk  = (const float*)d_in[3];
  const float* bk  = (const float*)d_in[4];
  const float* wv  = (const float*)d_in[5];
  const float* bv  = (const float*)d_in[6];
  const float* wo  = (const float*)d_in[7];
  const float* bo  = (const float*)d_in[8];
  const float* tau = (const float*)d_in[9];

  char* ws = (char*)d_ws;
  // layout (bytes) — no aliasing needed (306 MB total < proven ws >= 425 MB)
  unsigned short* xb    = (unsigned short*)(ws + 0L);          // 100663296
  unsigned short* xbT   = (unsigned short*)(ws + 100663296L);  // 100663296
  unsigned short* S     = (unsigned short*)(ws + 201326592L);  // 16*768*768*2 = 18874368
  unsigned short* T     = (unsigned short*)(ws + 220200960L);  // 16*1536*768*2 = 37748736
  unsigned short* W2    = (unsigned short*)(ws + 257949696L);  // 2359296
  unsigned short* wvT   = (unsigned short*)(ws + 260308992L);  // 1179648
  float*          zeros = (float*)         (ws + 261488640L);  // 4096
  float*          xsum  = (float*)         (ws + 261492736L);  // 49152
  float*          Gp    = (float*)         (ws + 261541888L);  // 512*2464*4 = 5046272
  unsigned short* A_ws  = (unsigned short*)(ws + 266588160L);  // 1572864
  unsigned short* btf   = (unsigned short*)(ws + 268161024L);  // 18874368
  unsigned short* Ctf   = (unsigned short*)(ws + 287035392L);  // 18874368
  float*          bias2 = (float*)         (ws + 305909760L);  // 49152 -> ends 305958912
  if (ws_size < 305958912ULL) return;

  transpose_cast_x<<<dim3(64, 12, BB), 256, 0, stream>>>(x, xb, xbT);
  small_cast<<<721, 256, 0, stream>>>(wq, wk, wv, W2, wvT, zeros);
  colsum<<<dim3(192, BB), 256, 0, stream>>>(xbT, xsum);

  // S[b] = x[b]^T x[b]  (768x768 symmetric, K=4096): 21 triangle tiles/batch
  gemm_bt<1, 1><<<16 * 21, 256, 0, stream>>>(
      xbT, NN, (long)DD * NN, xbT, NN, (long)DD * NN,
      S, DD, (long)DD * DD, zeros, 0L, NN, 21, 6);

  // T[b] = W2 * S[b]  (1536x768, K=768; S symmetric -> Bt=S), bf16 out
  gemm_bt<1, 0><<<16 * 72, 256, 0, stream>>>(
      W2, DD, 0L, S, DD, (long)DD * DD,
      T, DD, (long)1536 * DD, zeros, 0L, DD, 72, 6);

  energy_partial2<<<dim3(2, HH, BB), 256, 0, stream>>>(T, W2, Gp);
  energy_finish2<<<dim3(HH, BB), 256, 0, stream>>>(Gp, xsum, wq, wk, bq, bk, tau, A_ws);

  build_btf<<<dim3(6, HH, BB), 256, 0, stream>>>(A_ws, wo, btf);
  build_bias2<<<dim3(192, BB), 256, 0, stream>>>(btf, bv, bo, bias2);

  // Ctf[b] = Btf[b] * wv  (768x768, K=768), bf16 out
  gemm_bt<1, 0><<<16 * 36, 256, 0, stream>>>(
      btf, DD, (long)DD * DD, wvT, DD, 0L,
      Ctf, DD, (long)DD * DD, zeros, 0L, DD, 36, 6);

  // out[b] = x[b] * Ctf[b]^T + bias2[b]  (4096x768, K=768), f32 out
  gemm_bt<0, 0><<<16 * 192, 256, 0, stream>>>(
      xb, DD, (long)NN * DD, Ctf, DD, (long)DD * DD,
      d_out, DD, (long)NN * DD, bias2, (long)DD, DD, 192, 6);
}